// Round 6
// baseline (54.721 us; speedup 1.0000x reference)
//
#include <hip/hip_runtime.h>
#include <math.h>

#define NCLS   20
#define MCELLS 49
#define FEAT   30
#define ITEMF  1470   // MCELLS * FEAT

typedef unsigned long long u64;
typedef unsigned int u32;
typedef float f32x4 __attribute__((ext_vector_type(4)));

__device__ __forceinline__ void nts(float* p, float v) { __builtin_nontemporal_store(v, p); }

__global__ __launch_bounds__(256) void yolo_post(const float* __restrict__ x,
                                                 float* __restrict__ out,
                                                 int N) {
  const int wave = threadIdx.x >> 6;
  const int lane = threadIdx.x & 63;
  const int n = blockIdx.x * 4 + wave;

  // per-wave box tables for the all-pairs NMS (broadcast-read pattern)
  __shared__ float4 sbox[4][MCELLS];
  __shared__ float2 smeta[4][MCELLS];

  if (n >= N) return;   // wave-uniform exit; no block-wide barriers used

  const float* item = x + (size_t)n * ITEMF;

  // ---- output section pointers (flat concat in return order) ----
  const size_t NM = (size_t)N * MCELLS;
  float* out0 = out;              // class_logits  N*M*20
  float* out1 = out0 + NM * 20;   // yolo_bboxes   N*M*5
  float* out2 = out1 + NM * 5;    // boxes         N*M*4
  float* out3 = out2 + NM * 4;    // scores        N*M
  float* out4 = out3 + NM;        // labels        N*M
  float* out5 = out4 + NM;        // keep_mask     N*M
  float* out6 = out5 + NM;        // reserve_mask  N*M

  const int m = lane;
  const bool cellv = (m < MCELLS);

  // ---- per-lane AoS loads: lane m owns cell m's 30 floats (15x float2, 8B-aligned) ----
  float2 v[15];
  if (cellv) {
    const float2* Lp = (const float2*)(item + m * FEAT);
#pragma unroll
    for (int j = 0; j < 15; ++j) v[j] = Lp[j];
  } else {
#pragma unroll
    for (int j = 0; j < 15; ++j) v[j] = make_float2(0.f, 0.f);
  }

  // ---- class logits copy: global->global gather (reads are L1/L2 hits), NT stores ----
  {
    float* dst = out0 + (size_t)n * (MCELLS * NCLS);
#pragma unroll
    for (int i = 0; i < 16; ++i) {
      int idx = lane + i * 64;
      if (idx < MCELLS * NCLS) {
        int c = idx / NCLS;
        int k = idx - c * NCLS;
        nts(dst + idx, item[c * FEAT + k]);
      }
    }
  }

  // ---- per-cell compute ----
  int   labi = 0;
  float conf = 0.f;
  float x0 = 0.f, y0 = 0.f, x1 = 0.f, y1 = 0.f;
  bool  reserve = false;

  if (cellv) {
    // label = argmax over 20 logits (first-max), == argmax(softmax)
    float bestv = v[0].x;
    if (v[0].y > bestv) { bestv = v[0].y; labi = 1; }
#pragma unroll
    for (int j = 1; j < 10; ++j) {
      if (v[j].x > bestv) { bestv = v[j].x; labi = 2 * j; }
      if (v[j].y > bestv) { bestv = v[j].y; labi = 2 * j + 1; }
    }

    // bbox block elems 20..29: v[10].x=bx0 .y=by0 v[11].x=bw0 .y=bh0 v[12].x=c0
    //                          v[12].y=bx1 v[13].x=by1 .y=bw1 v[14].x=bh1 .y=c1
    float c0 = v[12].x, c1 = v[14].y;
    bool sel1 = (c1 > c0);             // argmax first-max tie rule
    float bx = sel1 ? v[12].y : v[10].x;
    float by = sel1 ? v[13].x : v[10].y;
    float bw = sel1 ? v[13].y : v[11].x;
    float bh = sel1 ? v[14].x : v[11].y;
    conf = sel1 ? c1 : c0;

    float xg = (float)(m % 7), yg = (float)(m / 7);
    float cx = (bx + xg) / 7.0f, cy = (by + yg) / 7.0f;
    float hw = bw * 0.5f, hh = bh * 0.5f;
    x0 = fminf(fmaxf((cx - hw) * 448.0f, 0.f), 448.f);
    y0 = fminf(fmaxf((cy - hh) * 448.0f, 0.f), 448.f);
    x1 = fminf(fmaxf((cx + hw) * 448.0f, 0.f), 448.f);
    y1 = fminf(fmaxf((cy + hh) * 448.0f, 0.f), 448.f);
    reserve = (conf > 0.1f);

    size_t ci = (size_t)n * MCELLS + m;
    float* yb = out1 + ci * 5;
    nts(yb + 0, bx); nts(yb + 1, by); nts(yb + 2, bw); nts(yb + 3, bh); nts(yb + 4, conf);
    f32x4 bx4 = { x0, y0, x1, y1 };
    __builtin_nontemporal_store(bx4, (f32x4*)(out2 + ci * 4));
    nts(out3 + ci, conf);
    nts(out4 + ci, (float)labi);
    nts(out6 + ci, reserve ? 1.0f : 0.0f);

    // stage this cell's box for the all-pairs pass
    sbox[wave][m]  = make_float4(x0, y0, x1, y1);
    smeta[wave][m] = make_float2(conf, __int_as_float(labi));
  }
  __threadfence_block();  // LDS writes visible before broadcast reads (wave-synchronous)

  // ================= NMS, sort-free =================
  // Greedy NMS == unique fixed point of: keep(i) <=> no kept candidate-suppressor.
  // cand(i) = { j : same label, strictly higher priority (score desc, idx asc),
  //             valid (conf>0.1), IoU > 0.7 }. Cross-label IoU is exactly 0 under
  // the reference's class-offset scheme, so labels partition the problem.
  const float area_i = fmaxf(x1 - x0, 0.f) * fmaxf(y1 - y0, 0.f);
  u64 cand = 0;
#pragma unroll 7
  for (int j = 0; j < MCELLS; ++j) {
    float4 bj = sbox[wave][j];     // wave-uniform broadcast read — no bank conflicts
    float2 mj = smeta[wave][j];
    float cj = mj.x;
    int  labj = __float_as_int(mj.y);
    bool prec = (labj == labi) && (cj > 0.1f) &&
                ((cj > conf) || ((cj == conf) && (j < m)));
    float aj = fmaxf(bj.z - bj.x, 0.f) * fmaxf(bj.w - bj.y, 0.f);
    float iw = fminf(bj.z, x1) - fmaxf(bj.x, x0);
    float ih = fminf(bj.w, y1) - fmaxf(bj.y, y0);
    float inter = fmaxf(iw, 0.f) * fmaxf(ih, 0.f);
    float uni = aj + area_i - inter;
    bool sup = prec && (inter > 0.7f * fmaxf(uni, 1e-9f));
    cand |= sup ? (1ull << j) : 0ull;
  }
  if (!(cellv && reserve)) cand = 0;

  // fixed-point resolution over wave-uniform bitmasks; the highest-priority
  // undecided box is always ready -> guaranteed progress (<= depth rounds).
  u64 valid = __ballot(cellv && reserve);
  u64 undecided = valid;
  u64 kept = 0;
  bool meValid = (cellv && reserve);
  while (undecided) {
    bool meUnd = meValid && ((undecided >> lane) & 1ull);
    bool ready = meUnd && ((cand & undecided) == 0ull);
    u64 readyb = __ballot(ready);
    u64 keptb  = __ballot(ready && ((cand & kept) == 0ull));
    kept |= keptb;
    undecided &= ~readyb;
  }

  if (cellv) nts(out5 + (size_t)n * MCELLS + m, (float)((kept >> lane) & 1ull));
}

extern "C" void kernel_launch(void* const* d_in, const int* in_sizes, int n_in,
                              void* d_out, int out_size, void* d_ws, size_t ws_size,
                              hipStream_t stream) {
  const float* x = (const float*)d_in[0];
  float* out = (float*)d_out;
  int N = in_sizes[0] / ITEMF;
  int grid = (N + 3) / 4;   // 4 waves/block, 1 item/wave
  yolo_post<<<grid, 256, 0, stream>>>(x, out, N);
}

// Round 7
// 44.808 us; speedup vs baseline: 1.2213x; 1.2213x over previous
//
#include <hip/hip_runtime.h>
#include <math.h>

#define NCLS   20
#define MCELLS 49
#define FEAT   30
#define ITEMF  1470   // MCELLS * FEAT

typedef unsigned long long u64;
typedef unsigned int u32;
typedef float f32x4 __attribute__((ext_vector_type(4)));

__device__ __forceinline__ int bcasti(int v, int l) {
  return __builtin_amdgcn_readlane(v, l);
}
__device__ __forceinline__ void nts(float* p, float v) { __builtin_nontemporal_store(v, p); }

__global__ __launch_bounds__(256) void yolo_post(const float* __restrict__ x,
                                                 float* __restrict__ out,
                                                 int N) {
  const int wave = threadIdx.x >> 6;
  const int lane = threadIdx.x & 63;
  const int n = blockIdx.x * 4 + wave;

  __shared__ float ldsAll[4][ITEMF];   // 23520 B / block

  if (n >= N) return;   // wave-uniform exit; no block-wide barriers used

  float* L = ldsAll[wave];

  // ---- stage item to LDS: coalesced float2 loads (each instr spans ~8 lines) ----
  {
    const float2* src = (const float2*)(x) + (size_t)n * (ITEMF / 2);
    float2* Ld = (float2*)L;
#pragma unroll
    for (int i = 0; i < 12; ++i) {
      int idx = lane + i * 64;
      if (idx < ITEMF / 2) Ld[idx] = src[idx];
    }
  }
  __threadfence_block();  // LDS writes visible before cross-lane reads (wave-synchronous)

  // ---- output section pointers (flat concat in return order) ----
  const size_t NM = (size_t)N * MCELLS;
  float* out0 = out;              // class_logits  N*M*20
  float* out1 = out0 + NM * 20;   // yolo_bboxes   N*M*5
  float* out2 = out1 + NM * 5;    // boxes         N*M*4
  float* out3 = out2 + NM * 4;    // scores        N*M
  float* out4 = out3 + NM;        // labels        N*M
  float* out5 = out4 + NM;        // keep_mask     N*M
  float* out6 = out5 + NM;        // reserve_mask  N*M

  // ---- class logits copy: LDS -> global, coalesced NT stores ----
  {
    float* dst = out0 + (size_t)n * (MCELLS * NCLS);
#pragma unroll
    for (int i = 0; i < 16; ++i) {
      int idx = lane + i * 64;
      if (idx < MCELLS * NCLS) {
        int c = idx / NCLS;
        int k = idx - c * NCLS;
        nts(dst + idx, L[c * FEAT + k]);
      }
    }
  }

  // ---- per-cell compute (lane m = cell m), reads from LDS ----
  const int m = lane;
  const bool cellv = (m < MCELLS);

  int   labi = 0;
  float conf = 0.f;
  float x0 = 0.f, y0 = 0.f, x1 = 0.f, y1 = 0.f;
  bool  reserve = false;

  if (cellv) {
    const float2* Lp = (const float2*)(L + m * FEAT);  // 8B-aligned (m*120B)
    float2 v[15];
#pragma unroll
    for (int j = 0; j < 15; ++j) v[j] = Lp[j];

    // label = argmax over 20 logits (first-max), == argmax(softmax)
    float bestv = v[0].x;
    if (v[0].y > bestv) { bestv = v[0].y; labi = 1; }
#pragma unroll
    for (int j = 1; j < 10; ++j) {
      if (v[j].x > bestv) { bestv = v[j].x; labi = 2 * j; }
      if (v[j].y > bestv) { bestv = v[j].y; labi = 2 * j + 1; }
    }

    // bbox block elems 20..29: v[10].x=bx0 .y=by0 v[11].x=bw0 .y=bh0 v[12].x=c0
    //                          v[12].y=bx1 v[13].x=by1 .y=bw1 v[14].x=bh1 .y=c1
    float c0 = v[12].x, c1 = v[14].y;
    bool sel1 = (c1 > c0);             // argmax first-max tie rule
    float bx = sel1 ? v[12].y : v[10].x;
    float by = sel1 ? v[13].x : v[10].y;
    float bw = sel1 ? v[13].y : v[11].x;
    float bh = sel1 ? v[14].x : v[11].y;
    conf = sel1 ? c1 : c0;

    float xg = (float)(m % 7), yg = (float)(m / 7);
    float cx = (bx + xg) / 7.0f, cy = (by + yg) / 7.0f;
    float hw = bw * 0.5f, hh = bh * 0.5f;
    x0 = fminf(fmaxf((cx - hw) * 448.0f, 0.f), 448.f);
    y0 = fminf(fmaxf((cy - hh) * 448.0f, 0.f), 448.f);
    x1 = fminf(fmaxf((cx + hw) * 448.0f, 0.f), 448.f);
    y1 = fminf(fmaxf((cy + hh) * 448.0f, 0.f), 448.f);
    reserve = (conf > 0.1f);

    size_t ci = (size_t)n * MCELLS + m;
    float* yb = out1 + ci * 5;
    nts(yb + 0, bx); nts(yb + 1, by); nts(yb + 2, bw); nts(yb + 3, bh); nts(yb + 4, conf);
    f32x4 bx4 = { x0, y0, x1, y1 };
    __builtin_nontemporal_store(bx4, (f32x4*)(out2 + ci * 4));
    nts(out3 + ci, conf);
    nts(out4 + ci, (float)labi);
    nts(out6 + ci, reserve ? 1.0f : 0.0f);
  }

  // ================= NMS =================
  // Cross-class IoU is exactly 0 under the reference's class-offset scheme,
  // so the global greedy scan == independent per-class greedy scans.
  // Sort by (label asc, score desc, idx asc) via a single u64 key; invalid -> ~0.
  u64 key;
  if (cellv && reserve) {
    u32 sb = __float_as_uint(conf);            // conf in (0.1,1): monotone bits
    u32 inv = 0x7FFFFFFFu - sb;                // descending score -> ascending field
    key = ((u64)labi << 37) | ((u64)inv << 6) | (u64)lane;
  } else {
    key = ~0ull;
  }

  // bitonic sort, 64 lanes, ascending
#pragma unroll
  for (int k = 2; k <= 64; k <<= 1) {
#pragma unroll
    for (int j = k >> 1; j >= 1; j >>= 1) {
      u64 ok = __shfl(key, lane ^ j);
      bool lower = (lane & j) == 0;
      bool asc = (lane & k) == 0;
      if ((key > ok) == (lower == asc)) key = ok;
    }
  }

  const int sid  = (int)(key & 63);
  const int slab = (int)((key >> 37) & 31);   // 31 for invalid

  // gather sorted coords
  float gx0 = __shfl(x0, sid), gy0 = __shfl(y0, sid);
  float gx1 = __shfl(x1, sid), gy1 = __shfl(y1, sid);
  float garea = fmaxf(gx1 - gx0, 0.f) * fmaxf(gy1 - gy0, 0.f);

  // max same-class run length (runs are contiguous after the sort) -> rotation bound.
  int prevlab = __shfl(slab, (lane + 63) & 63);
  bool rstart = (lane == 0) || (prevlab != slab);
  u64 S = __ballot(rstart);                       // bit 0 always set
  u64 le_mask = (lane == 63) ? ~0ull : ((2ull << lane) - 1ull);
  int st = 63 - __builtin_clzll(S & le_mask);     // my run's start lane
  u64 gt = (lane == 63) ? 0ull : (S >> (lane + 1));
  int nxt = gt ? (lane + 1 + (int)__builtin_ctzll(gt)) : 64;
  int rl = (slab != 31) ? (nxt - st) : 1;
#pragma unroll
  for (int d2 = 1; d2 < 64; d2 <<= 1) {
    int o = __shfl_xor(rl, d2);
    rl = rl > o ? rl : o;
  }
  const int Dmax = __builtin_amdgcn_readfirstlane(rl);

  // parallel suppression-row masks via rotations, ballot-free
  u64 rowm = 0;
  for (int d = 1; d < Dmax; ++d) {
    int srcl = (lane + d) & 63;
    int plab = __shfl(slab, srcl);
    float px0 = __shfl(gx0, srcl), py0 = __shfl(gy0, srcl);
    float px1 = __shfl(gx1, srcl), py1 = __shfl(gy1, srcl);
    float pa  = __shfl(garea, srcl);
    bool match = (plab == slab) && (slab != 31) && (lane + d < 64);
    float iw = fmaxf(fminf(px1, gx1) - fmaxf(px0, gx0), 0.f);
    float ih = fmaxf(fminf(py1, gy1) - fmaxf(py0, gy0), 0.f);
    float inter = iw * ih;
    float uni = pa + garea - inter;
    bool ok = match && (inter > 0.7f * fmaxf(uni, 1e-9f));
    rowm |= ok ? (1ull << srcl) : 0ull;
  }

  // greedy scan over sorted order, skipping suppressed via ctz (iters = #kept)
  int V = __popcll(__ballot(key != ~0ull));       // valids occupy lanes 0..V-1
  int rlo = (int)(rowm & 0xFFFFFFFFull), rhi = (int)(rowm >> 32);
  u64 remaining = (V >= 64) ? ~0ull : ((1ull << V) - 1ull);
  u64 keep = 0;
  while (remaining) {
    int i = (int)__builtin_ctzll(remaining);
    keep |= 1ull << i;
    u64 rm = ((u64)(u32)bcasti(rhi, i) << 32) | (u32)bcasti(rlo, i);
    remaining &= ~(rm | (1ull << i));
  }

  // scatter keep bit (sorted lane -> original cell lane) via ds_permute
  int kb = (int)((keep >> lane) & 1ull);
  int kf = __builtin_amdgcn_ds_permute(sid << 2, __float_as_int((float)kb));
  if (cellv) nts(out5 + (size_t)n * MCELLS + m, __int_as_float(kf));
}

extern "C" void kernel_launch(void* const* d_in, const int* in_sizes, int n_in,
                              void* d_out, int out_size, void* d_ws, size_t ws_size,
                              hipStream_t stream) {
  const float* x = (const float*)d_in[0];
  float* out = (float*)d_out;
  int N = in_sizes[0] / ITEMF;
  int grid = (N + 3) / 4;   // 4 waves/block, 1 item/wave
  yolo_post<<<grid, 256, 0, stream>>>(x, out, N);
}

// Round 8
// 40.607 us; speedup vs baseline: 1.3476x; 1.1034x over previous
//
#include <hip/hip_runtime.h>
#include <math.h>

#define NCLS   20
#define MCELLS 49
#define FEAT   30
#define ITEMF  1470   // MCELLS * FEAT

typedef unsigned long long u64;
typedef unsigned int u32;
typedef float f32x4 __attribute__((ext_vector_type(4)));

__device__ __forceinline__ void nts(float* p, float v) { __builtin_nontemporal_store(v, p); }
__device__ __forceinline__ float bperm(int srcLane, float v) {
  return __int_as_float(__builtin_amdgcn_ds_bpermute(srcLane << 2, __float_as_int(v)));
}

__global__ __launch_bounds__(256) void yolo_post(const float* __restrict__ x,
                                                 float* __restrict__ out,
                                                 int N) {
  const int wave = threadIdx.x >> 6;
  const int lane = threadIdx.x & 63;
  const int n = blockIdx.x * 4 + wave;
  if (n >= N) return;   // wave-uniform exit; no LDS, no barriers

  const float* item = x + (size_t)n * ITEMF;

  // ---- output section pointers (flat concat in return order) ----
  const size_t NM = (size_t)N * MCELLS;
  float* out0 = out;              // class_logits  N*M*20
  float* out1 = out0 + NM * 20;   // yolo_bboxes   N*M*5
  float* out2 = out1 + NM * 5;    // boxes         N*M*4
  float* out3 = out2 + NM * 4;    // scores        N*M
  float* out4 = out3 + NM;        // labels        N*M
  float* out5 = out4 + NM;        // keep_mask     N*M
  float* out6 = out5 + NM;        // reserve_mask  N*M

  const int m = lane;
  const bool cellv = (m < MCELLS);

  // ---- per-lane AoS loads: lane m owns cell m's 30 floats (15x float2, 8B-aligned) ----
  float2 v[15];
  if (cellv) {
    const float2* Lp = (const float2*)(item + m * FEAT);
#pragma unroll
    for (int j = 0; j < 15; ++j) v[j] = Lp[j];
  } else {
#pragma unroll
    for (int j = 0; j < 15; ++j) v[j] = make_float2(0.f, 0.f);
  }

  // ---- class logits copy: global->global gather (reads are L1/L2 hits), NT stores ----
  {
    float* dst = out0 + (size_t)n * (MCELLS * NCLS);
#pragma unroll
    for (int i = 0; i < 16; ++i) {
      int idx = lane + i * 64;
      if (idx < MCELLS * NCLS) {
        int c = idx / NCLS;
        int k = idx - c * NCLS;
        nts(dst + idx, item[c * FEAT + k]);
      }
    }
  }

  // ---- per-cell compute ----
  int   labi = 0;
  float conf = 0.f;
  float x0 = 0.f, y0 = 0.f, x1 = 0.f, y1 = 0.f;
  bool  reserve = false;

  if (cellv) {
    // label = argmax over 20 logits (first-max), == argmax(softmax)
    float bestv = v[0].x;
    if (v[0].y > bestv) { bestv = v[0].y; labi = 1; }
#pragma unroll
    for (int j = 1; j < 10; ++j) {
      if (v[j].x > bestv) { bestv = v[j].x; labi = 2 * j; }
      if (v[j].y > bestv) { bestv = v[j].y; labi = 2 * j + 1; }
    }

    // bbox block elems 20..29: v[10].x=bx0 .y=by0 v[11].x=bw0 .y=bh0 v[12].x=c0
    //                          v[12].y=bx1 v[13].x=by1 .y=bw1 v[14].x=bh1 .y=c1
    float c0 = v[12].x, c1 = v[14].y;
    bool sel1 = (c1 > c0);             // argmax first-max tie rule
    float bx = sel1 ? v[12].y : v[10].x;
    float by = sel1 ? v[13].x : v[10].y;
    float bw = sel1 ? v[13].y : v[11].x;
    float bh = sel1 ? v[14].x : v[11].y;
    conf = sel1 ? c1 : c0;

    float xg = (float)(m % 7), yg = (float)(m / 7);
    float cx = (bx + xg) / 7.0f, cy = (by + yg) / 7.0f;
    float hw = bw * 0.5f, hh = bh * 0.5f;
    x0 = fminf(fmaxf((cx - hw) * 448.0f, 0.f), 448.f);
    y0 = fminf(fmaxf((cy - hh) * 448.0f, 0.f), 448.f);
    x1 = fminf(fmaxf((cx + hw) * 448.0f, 0.f), 448.f);
    y1 = fminf(fmaxf((cy + hh) * 448.0f, 0.f), 448.f);
    reserve = (conf > 0.1f);

    size_t ci = (size_t)n * MCELLS + m;
    float* yb = out1 + ci * 5;
    nts(yb + 0, bx); nts(yb + 1, by); nts(yb + 2, bw); nts(yb + 3, bh); nts(yb + 4, conf);
    f32x4 bx4 = { x0, y0, x1, y1 };
    __builtin_nontemporal_store(bx4, (f32x4*)(out2 + ci * 4));
    nts(out3 + ci, conf);
    nts(out4 + ci, (float)labi);
    nts(out6 + ci, reserve ? 1.0f : 0.0f);
  }

  // ================= NMS: sort-free, scan-free =================
  // Cross-label IoU is exactly 0 under the reference's class-offset scheme, so
  // the greedy scan == per-class greedy; keep(i) is the unique fixed point of
  // keep(i) <=> no kept candidate-suppressor (same label, higher priority, IoU>0.7).
  const bool meValid = (cellv && reserve);
  const u64 validb = __ballot(meValid);

  // same-label mask via 5 bit-ballots over the label bits (labi < 32)
  u64 same = ~0ull;
#pragma unroll
  for (int b = 0; b < 5; ++b) {
    u64 bb = __ballot(((labi >> b) & 1) != 0);
    same &= ((labi >> b) & 1) ? bb : ~bb;
  }
  u64 peers = same & validb & ~(1ull << lane);
  if (!meValid) peers = 0;

  // wave-uniform trip count = max peer count over the wave
  int pc = __popcll(peers);
#pragma unroll
  for (int d = 1; d < 64; d <<= 1) {
    int o = __shfl_xor(pc, d);
    pc = pc > o ? pc : o;
  }
  const int T = __builtin_amdgcn_readfirstlane(pc);

  // candidate-suppressor mask in ORIGINAL index space; iterations pipeline
  const float area_i = fmaxf(x1 - x0, 0.f) * fmaxf(y1 - y0, 0.f);
  u64 candme = 0;
  u64 rem = peers;
  for (int t = 0; t < T; ++t) {
    int j = rem ? (int)__builtin_ctzll(rem) : lane;   // dummy self-compare when exhausted
    rem &= rem - 1;
    float cj  = bperm(j, conf);
    float jx0 = bperm(j, x0), jy0 = bperm(j, y0);
    float jx1 = bperm(j, x1), jy1 = bperm(j, y1);
    bool prec = (cj > conf) || ((cj == conf) && (j < lane));  // stable-sort priority
    float aj = fmaxf(jx1 - jx0, 0.f) * fmaxf(jy1 - jy0, 0.f);
    float iw = fminf(jx1, x1) - fmaxf(jx0, x0);
    float ih = fminf(jy1, y1) - fmaxf(jy0, y0);
    float inter = fmaxf(iw, 0.f) * fmaxf(ih, 0.f);
    float uni = aj + area_i - inter;
    bool sup = prec && (inter > 0.7f * fmaxf(uni, 1e-9f));
    candme |= sup ? (1ull << j) : 0ull;
  }

  // ballot fixed-point: per class, the highest-priority undecided box is always
  // ready -> guaranteed progress; rounds <= max suppression-chain depth (~2-3).
  u64 undecided = validb, kept = 0;
  while (undecided) {
    bool meUnd  = meValid && ((undecided >> lane) & 1ull);
    bool ready  = meUnd && ((candme & undecided) == 0ull);
    u64 readyb  = __ballot(ready);
    u64 keptb   = __ballot(ready && ((candme & kept) == 0ull));
    kept |= keptb;
    undecided &= ~readyb;
  }

  if (cellv) nts(out5 + (size_t)n * MCELLS + m, (float)((kept >> lane) & 1ull));
}

extern "C" void kernel_launch(void* const* d_in, const int* in_sizes, int n_in,
                              void* d_out, int out_size, void* d_ws, size_t ws_size,
                              hipStream_t stream) {
  const float* x = (const float*)d_in[0];
  float* out = (float*)d_out;
  int N = in_sizes[0] / ITEMF;
  int grid = (N + 3) / 4;   // 4 waves/block, 1 item/wave
  yolo_post<<<grid, 256, 0, stream>>>(x, out, N);
}